// Round 4
// baseline (41.475 us; speedup 1.0000x reference)
//
#include <hip/hip_runtime.h>

#define NB 8
#define NC 4
#define NH 256
#define NW 256
#define HW (NH * NW)      // 65536
#define CHW (NC * HW)     // 262144
#define INFV 1e10f
#define MAIN_BLOCKS (NB * 64)    // 8 batches x 8x8 tiles of 32x32 = 512

// ---------------------------------------------------------------------------
// K1: EDT pass 1 along W — ballot version. One block (256 thr) per (b,h).
// Exact: d^2 with d<=255, INFV if class absent from row.
// ---------------------------------------------------------------------------
__global__ __launch_bounds__(256) void k_edt_w(const int* __restrict__ tgt,
                                               float* __restrict__ D) {
    int bh = blockIdx.x;            // b*NH + h
    int i  = threadIdx.x;
    int wv = i >> 6;                // wave id (0..3)
    int ln = i & 63;

    int tv = tgt[(size_t)bh * NW + i];

    __shared__ unsigned long long mk[NC][4];
    #pragma unroll
    for (int c = 0; c < NC; ++c) {
        unsigned long long m = __ballot(tv == c);
        if (ln == 0) mk[c][wv] = m;
    }
    __syncthreads();

    unsigned long long le = (ln == 63) ? ~0ull : ((1ull << (ln + 1)) - 1ull);
    unsigned long long ge = ~0ull << ln;

    float res[NC];
    #pragma unroll
    for (int c = 0; c < NC; ++c) {
        int jl = -1000;
        #pragma unroll
        for (int k = 0; k < 4; ++k) {
            unsigned long long x = mk[c][k];
            x = (k > wv) ? 0ull : ((k == wv) ? (x & le) : x);
            if (x) jl = k * 64 + 63 - __clzll((long long)x);
        }
        int jr = 1000;
        #pragma unroll
        for (int k = 3; k >= 0; --k) {
            unsigned long long x = mk[c][k];
            x = (k < wv) ? 0ull : ((k == wv) ? (x & ge) : x);
            if (x) jr = k * 64 + __ffsll((unsigned long long)x) - 1;
        }
        int dl = i - jl;
        int dr = jr - i;
        int dd = min(dl, dr);
        res[c] = (dd > 255) ? INFV : (float)(dd * dd);
    }

    int b = bh >> 8;
    int h = bh & 255;
    size_t o = (size_t)b * CHW + (size_t)h * NW + i;
    D[o]          = res[0];
    D[o + HW]     = res[1];
    D[o + 2 * HW] = res[2];
    D[o + 3 * HW] = res[3];
}

// ---------------------------------------------------------------------------
// softmax of the 4 channel logits at pixel offset hw of batch-base pred_b.
// ---------------------------------------------------------------------------
__device__ __forceinline__ void softmax4(const float* __restrict__ pred_b,
                                         int hw, float o[NC]) {
    float x0 = pred_b[hw];
    float x1 = pred_b[hw + HW];
    float x2 = pred_b[hw + 2 * HW];
    float x3 = pred_b[hw + 3 * HW];
    float m  = fmaxf(fmaxf(x0, x1), fmaxf(x2, x3));
    float e0 = __expf(x0 - m);
    float e1 = __expf(x1 - m);
    float e2 = __expf(x2 - m);
    float e3 = __expf(x3 - m);
    float inv = 1.0f / (e0 + e1 + e2 + e3);
    o[0] = e0 * inv; o[1] = e1 * inv; o[2] = e2 * inv; o[3] = e3 * inv;
}

// ---------------------------------------------------------------------------
// K2: fused kernel, one block per 32x32 output tile.
//  - stage softmax p for the 34x34 halo in LDS (1.13 softmax/px vs 5/px)
//  - |laplacian| stencil from LDS (zero pad at image borders)
//  - EDT pass-2 per pixel: exact early-exit radial column scan of D
//  - block reduction -> partial[block]
// Threads: 256 as (32 wide x 8 tall), each handles 4 rows of the tile.
// ---------------------------------------------------------------------------
__global__ __launch_bounds__(256) void k_main(const float* __restrict__ pred,
                                              const float* __restrict__ D,
                                              float2* __restrict__ partial) {
    int tb   = blockIdx.x;          // b*64 + tile_y*8 + tile_x
    int b    = tb >> 6;
    int tile = tb & 63;
    int h0   = (tile >> 3) << 5;
    int w0   = (tile & 7) << 5;

    const float* pred_b = pred + (size_t)b * CHW;

    __shared__ float ps[NC][34][36];   // padded rows: conflict-free stencil
    for (int pos = threadIdx.x; pos < 34 * 34; pos += 256) {
        int row = pos / 34;
        int col = pos - row * 34;
        int gy = h0 - 1 + row;
        int gx = w0 - 1 + col;
        float o[NC] = {0.0f, 0.0f, 0.0f, 0.0f};   // zero pad outside image
        if (gy >= 0 && gy < NH && gx >= 0 && gx < NW)
            softmax4(pred_b, (gy << 8) + gx, o);
        ps[0][row][col] = o[0];
        ps[1][row][col] = o[1];
        ps[2][row][col] = o[2];
        ps[3][row][col] = o[3];
    }
    __syncthreads();

    int tx  = threadIdx.x & 31;
    int ty0 = threadIdx.x >> 5;        // 0..7
    int w   = w0 + tx;

    float num = 0.0f, den = 0.0f;
    #pragma unroll
    for (int k = 0; k < 4; ++k) {
        int ly = ty0 + (k << 3);       // 0..31
        int h  = h0 + ly;
        #pragma unroll
        for (int c = 0; c < NC; ++c) {
            float lap = fabsf(ps[c][ly][tx + 1] + ps[c][ly + 2][tx + 1]
                            + ps[c][ly + 1][tx] + ps[c][ly + 1][tx + 2]
                            - 4.0f * ps[c][ly + 1][tx + 1]);

            // exact column min: min_j (h-j)^2 + f[j], early exit r^2 >= best
            const float* f = D + (size_t)b * CHW + (size_t)c * HW + w;
            float best = f[h << 8];
            for (int r = 1; r < NH; ++r) {
                float rr = (float)(r * r);     // exact int <= 65025
                if (rr >= best) break;
                int hu = h - r, hd = h + r;
                if (hu >= 0) best = fminf(best, rr + f[hu << 8]);
                if (hd < NH) best = fminf(best, rr + f[hd << 8]);
            }
            float dv = (best > 1e8f) ? 0.0f : sqrtf(best); // empty-ch mask

            num += lap * dv;
            den += lap;
        }
    }

    #pragma unroll
    for (int off = 32; off > 0; off >>= 1) {
        num += __shfl_down(num, off);
        den += __shfl_down(den, off);
    }
    __shared__ float sn[4], sd[4];
    int lane = threadIdx.x & 63;
    int wvi  = threadIdx.x >> 6;
    if (lane == 0) { sn[wvi] = num; sd[wvi] = den; }
    __syncthreads();
    if (threadIdx.x == 0) {
        partial[blockIdx.x] = make_float2(sn[0] + sn[1] + sn[2] + sn[3],
                                          sd[0] + sd[1] + sd[2] + sd[3]);
    }
}

// ---------------------------------------------------------------------------
// K3: final reduction of partials + divide. One block.
// ---------------------------------------------------------------------------
__global__ __launch_bounds__(256) void k_final(const float2* __restrict__ partial,
                                               float* __restrict__ out) {
    double n = 0.0, d = 0.0;
    for (int i = threadIdx.x; i < MAIN_BLOCKS; i += 256) {
        float2 v = partial[i];
        n += (double)v.x;
        d += (double)v.y;
    }
    #pragma unroll
    for (int off = 32; off > 0; off >>= 1) {
        n += __shfl_down(n, off);
        d += __shfl_down(d, off);
    }
    __shared__ double snd[4], sdd[4];
    int lane = threadIdx.x & 63;
    int wv   = threadIdx.x >> 6;
    if (lane == 0) { snd[wv] = n; sdd[wv] = d; }
    __syncthreads();
    if (threadIdx.x == 0) {
        double nn = snd[0] + snd[1] + snd[2] + snd[3];
        double dd = sdd[0] + sdd[1] + sdd[2] + sdd[3];
        out[0] = (float)(nn / dd);
    }
}

extern "C" void kernel_launch(void* const* d_in, const int* in_sizes, int n_in,
                              void* d_out, int out_size, void* d_ws, size_t ws_size,
                              hipStream_t stream) {
    const float* pred = (const float*)d_in[0];
    const int*   tgt  = (const int*)d_in[1];
    float*       out  = (float*)d_out;

    float*  D       = (float*)d_ws;                     // 8 MB
    float2* partial = (float2*)(D + (size_t)NB * CHW);  // 4 KB

    k_edt_w<<<NB * NH,     256, 0, stream>>>(tgt, D);
    k_main <<<MAIN_BLOCKS, 256, 0, stream>>>(pred, D, partial);
    k_final<<<1,           256, 0, stream>>>(partial, out);
}